// Round 1
// baseline (1090.963 us; speedup 1.0000x reference)
//
#include <hip/hip_runtime.h>
#include <stdint.h>

typedef float f32x4 __attribute__((ext_vector_type(4)));
typedef short bf16x8 __attribute__((ext_vector_type(8)));

__device__ __forceinline__ unsigned short f2bf(float f) {
  union { float f; uint32_t u; } v; v.f = f;
  uint32_t r = v.u + 0x7FFFu + ((v.u >> 16) & 1u);
  return (unsigned short)(r >> 16);
}

// ---------- elementwise fp32 -> bf16 ----------
__global__ __launch_bounds__(256) void conv_f2b(const float* __restrict__ in,
                                                unsigned short* __restrict__ out, long n) {
  long i = ((long)blockIdx.x * 256 + threadIdx.x) * 4;
  if (i + 3 < n) {
    float4 f = *(const float4*)(in + i);
    ushort4 o;
    o.x = f2bf(f.x); o.y = f2bf(f.y); o.z = f2bf(f.z); o.w = f2bf(f.w);
    *(ushort4*)(out + i) = o;
  }
}

// ---------- batched tiled transpose fp32 [R,C] -> bf16 [C,R] ----------
__global__ __launch_bounds__(256) void transpose_f2b(const float* __restrict__ in,
                                                     unsigned short* __restrict__ out,
                                                     int R, int C) {
  __shared__ unsigned short tile[32][33];
  long base = (long)blockIdx.z * R * C;
  in += base; out += base;
  int c0 = blockIdx.x * 32, r0 = blockIdx.y * 32;
  int tx = threadIdx.x & 31, ty = threadIdx.x >> 5;  // ty: 0..7
#pragma unroll
  for (int i = 0; i < 32; i += 8)
    tile[ty + i][tx] = f2bf(in[(long)(r0 + ty + i) * C + c0 + tx]);
  __syncthreads();
#pragma unroll
  for (int i = 0; i < 32; i += 8)
    out[(long)(c0 + ty + i) * R + r0 + tx] = tile[tx][ty + i];
}

// ---------- fused bias: bfused[j] = sum_r bph_flat[r]*Wproj[r,j] + bproj[j] ----------
__global__ __launch_bounds__(256) void bias_fuse(const float* __restrict__ bph,
                                                 const float* __restrict__ Wproj,
                                                 const float* __restrict__ bproj,
                                                 float* __restrict__ bfused) {
  int j = blockIdx.x * 256 + threadIdx.x;  // < 768
  int r0 = blockIdx.y * 256;
  float acc = 0.f;
  for (int r = r0; r < r0 + 256; r++)
    acc += bph[r] * Wproj[(long)r * 768 + j];
  if (blockIdx.y == 0) acc += bproj[j];
  atomicAdd(&bfused[j], acc);
}

// ---------- in-place softmax over rows of 512 (one wave per row) ----------
__global__ __launch_bounds__(256) void softmax512(float* __restrict__ p) {
  long row = (long)blockIdx.x * 4 + (threadIdx.x >> 6);
  int lane = threadIdx.x & 63;
  float* r = p + row * 512;
  float4 a = ((float4*)r)[lane];
  float4 b = ((float4*)r)[64 + lane];
  float m = fmaxf(fmaxf(fmaxf(a.x, a.y), fmaxf(a.z, a.w)),
                  fmaxf(fmaxf(b.x, b.y), fmaxf(b.z, b.w)));
#pragma unroll
  for (int off = 32; off; off >>= 1) m = fmaxf(m, __shfl_xor(m, off, 64));
  a.x = __expf(a.x - m); a.y = __expf(a.y - m); a.z = __expf(a.z - m); a.w = __expf(a.w - m);
  b.x = __expf(b.x - m); b.y = __expf(b.y - m); b.z = __expf(b.z - m); b.w = __expf(b.w - m);
  float s = a.x + a.y + a.z + a.w + b.x + b.y + b.z + b.w;
#pragma unroll
  for (int off = 32; off; off >>= 1) s += __shfl_xor(s, off, 64);
  float inv = 1.0f / s;
  a.x *= inv; a.y *= inv; a.z *= inv; a.w *= inv;
  b.x *= inv; b.y *= inv; b.z *= inv; b.w *= inv;
  ((float4*)r)[lane] = a;
  ((float4*)r)[64 + lane] = b;
}

// ---------- staging helpers (8 elements -> bf16 LDS) ----------
__device__ __forceinline__ void stage8(const unsigned short* __restrict__ g,
                                       unsigned short* __restrict__ s) {
  *(uint4*)s = *(const uint4*)g;
}
__device__ __forceinline__ void stage8(const float* __restrict__ g,
                                       unsigned short* __restrict__ s) {
  float4 f0 = *(const float4*)g;
  float4 f1 = *(const float4*)(g + 4);
  ushort4 o0, o1;
  o0.x = f2bf(f0.x); o0.y = f2bf(f0.y); o0.z = f2bf(f0.z); o0.w = f2bf(f0.w);
  o1.x = f2bf(f1.x); o1.y = f2bf(f1.y); o1.z = f2bf(f1.z); o1.w = f2bf(f1.w);
  *(ushort4*)s = o0;
  *(ushort4*)(s + 4) = o1;
}

// ---------- generic 64x64-tile MFMA GEMM: C = A[M,K] @ Bt[N,K]^T ----------
template <typename AT, typename Epi>
__global__ __launch_bounds__(256) void gemm_bt(const AT* __restrict__ A, long asb, int lda,
                                               const unsigned short* __restrict__ Bt, long bsb,
                                               int ldb, int K, Epi epi) {
  __shared__ __align__(16) unsigned short As[64][32];
  __shared__ __align__(16) unsigned short Bs[64][32];
  const int tid = threadIdx.x;
  const int row = tid >> 2;         // 0..63
  const int kc = (tid & 3) * 8;     // 0,8,16,24
  const int lane = tid & 63;
  const int w = tid >> 6;           // wave 0..3
  const int quad = lane >> 4, lr = lane & 15;
  const int bz = blockIdx.z;

  f32x4 acc[4];
#pragma unroll
  for (int i = 0; i < 4; i++) acc[i] = (f32x4){0.f, 0.f, 0.f, 0.f};

  const AT* Ab = A + (long)bz * asb + (long)(blockIdx.y * 64 + row) * lda;
  const unsigned short* Bb = Bt + (long)bz * bsb + (long)(blockIdx.x * 64 + row) * ldb;

  for (int k0 = 0; k0 < K; k0 += 32) {
    stage8(Ab + k0 + kc, &As[row][kc]);
    stage8(Bb + k0 + kc, &Bs[row][kc]);
    __syncthreads();
    bf16x8 a = *(const bf16x8*)&As[w * 16 + lr][quad * 8];
#pragma unroll
    for (int nt = 0; nt < 4; nt++) {
      bf16x8 b = *(const bf16x8*)&Bs[nt * 16 + lr][quad * 8];
      acc[nt] = __builtin_amdgcn_mfma_f32_16x16x32_bf16(a, b, acc[nt], 0, 0, 0);
    }
    __syncthreads();
  }
  const int mg = blockIdx.y * 64 + w * 16 + quad * 4;
  const int ng = blockIdx.x * 64 + lr;
#pragma unroll
  for (int nt = 0; nt < 4; nt++)
#pragma unroll
    for (int r = 0; r < 4; r++)
      epi(bz, mg + r, ng + nt * 16, acc[nt][r]);
}

// ---------- epilogues ----------
struct EpiQKV {  // n = h*192 + d3; scatter to q,k (row-major [BH,T,D]) and v^T ([BH,D,T])
  const float* bqkv;
  unsigned short *q, *k, *vt;
  __device__ void operator()(int, int m, int n, float val) const {
    int h = n / 192, d3 = n - h * 192;
    unsigned short bv = f2bf(val + bqkv[n]);
    int b = m >> 9, t = m & 511;
    long bh = b * 12 + h;
    if (d3 < 64)        q[(bh * 512 + t) * 64 + d3] = bv;
    else if (d3 < 128)  k[(bh * 512 + t) * 64 + (d3 - 64)] = bv;
    else                vt[(bh * 64 + (d3 - 128)) * 512 + t] = bv;
  }
};
struct EpiScore {  // scaled logits into d_out probs region [BH,T,T]
  float* probs;
  __device__ void operator()(int z, int m, int n, float val) const {
    probs[(long)z * 262144 + (long)m * 512 + n] = val * 0.125f;
  }
};
struct EpiPV {  // sa_flat bf16 [B*T, H*D]
  unsigned short* sa;
  __device__ void operator()(int z, int m, int n, float val) const {
    int b = z / 12, h = z - b * 12;
    sa[((long)(b * 512 + m)) * 768 + h * 64 + n] = f2bf(val);
  }
};
struct EpiWf {  // Wfused^T bf16 [768 j, 768 hd]; z = h, m = d
  unsigned short* wft;
  __device__ void operator()(int z, int m, int n, float val) const {
    wft[(long)n * 768 + z * 64 + m] = f2bf(val);
  }
};
struct EpiOut {  // final fp32 output + fused bias
  float* out;
  const float* bfused;
  __device__ void operator()(int, int m, int n, float val) const {
    out[(long)m * 768 + n] = val + bfused[n];
  }
};

extern "C" void kernel_launch(void* const* d_in, const int* in_sizes, int n_in,
                              void* d_out, int out_size, void* d_ws, size_t ws_size,
                              hipStream_t stream) {
  const float* x     = (const float*)d_in[0];
  const float* Wqkv  = (const float*)d_in[1];
  const float* bqkv  = (const float*)d_in[2];
  const float* Wph   = (const float*)d_in[3];
  const float* bph   = (const float*)d_in[4];
  const float* Wproj = (const float*)d_in[5];
  const float* bproj = (const float*)d_in[6];
  float* out = (float*)d_out;
  float* probs = out + 12582912L;  // [32,12,512,512]

  char* ws = (char*)d_ws;
  auto alloc = [&](size_t bytes) {
    char* p = ws;
    ws += (bytes + 255) & ~(size_t)255;
    return p;
  };
  unsigned short* x_b    = (unsigned short*)alloc(16384L * 768 * 2);
  unsigned short* wqkvt  = (unsigned short*)alloc(2304L * 768 * 2);
  unsigned short* wph_b  = (unsigned short*)alloc(768L * 768 * 2);
  unsigned short* wprojt = (unsigned short*)alloc(768L * 9216 * 2);
  unsigned short* wft    = (unsigned short*)alloc(768L * 768 * 2);
  float*          bfused = (float*)alloc(768 * 4);
  unsigned short* qb     = (unsigned short*)alloc(12582912L * 2);
  unsigned short* kb     = (unsigned short*)alloc(12582912L * 2);
  unsigned short* vtb    = (unsigned short*)alloc(12582912L * 2);
  unsigned short* sa     = (unsigned short*)alloc(12582912L * 2);

  hipMemsetAsync(bfused, 0, 768 * 4, stream);

  // pack/convert
  conv_f2b<<<12288, 256, 0, stream>>>(x, x_b, 12582912L);
  conv_f2b<<<576, 256, 0, stream>>>(Wph, wph_b, 589824L);
  transpose_f2b<<<dim3(6, 24, 12), 256, 0, stream>>>(Wqkv, wqkvt, 768, 192);
  transpose_f2b<<<dim3(24, 288, 1), 256, 0, stream>>>(Wproj, wprojt, 9216, 768);
  bias_fuse<<<dim3(3, 36), 256, 0, stream>>>(bph, Wproj, bproj, bfused);

  // QKV projection: [16384,768] @ [2304,768]^T, scatter epilogue
  gemm_bt<<<dim3(36, 256, 1), 256, 0, stream>>>(x_b, 0L, 768, wqkvt, 0L, 768, 768,
                                                EpiQKV{bqkv, qb, kb, vtb});
  // scores: per (b,h): [512,64] @ [512,64]^T -> scaled logits in d_out
  gemm_bt<<<dim3(8, 8, 384), 256, 0, stream>>>(qb, 32768L, 64, kb, 32768L, 64, 64,
                                               EpiScore{probs});
  // softmax in place (one wave per row)
  softmax512<<<49152, 256, 0, stream>>>(probs);
  // PV: per (b,h): [512,512](fp32 probs) @ [64,512]^T(v^T) -> sa_flat bf16
  gemm_bt<<<dim3(1, 8, 384), 256, 0, stream>>>(probs, 262144L, 512, vtb, 32768L, 512, 512,
                                               EpiPV{sa});
  // Wfused^T: per h: Wph_h[64,768] @ Wproj_t[:, h*768:+768]^T
  gemm_bt<<<dim3(12, 1, 12), 256, 0, stream>>>(wph_b, 49152L, 768, wprojt, 768L, 9216, 768,
                                               EpiWf{wft});
  // final: [16384,768] @ [768,768]^T + bfused -> d_out
  gemm_bt<<<dim3(12, 256, 1), 256, 0, stream>>>(sa, 0L, 768, wft, 0L, 768, 768,
                                                EpiOut{out, bfused});
}